// Round 3
// 705.728 us; speedup vs baseline: 1.0016x; 1.0016x over previous
//
#include <hip/hip_runtime.h>
#include <math.h>

// Problem constants (fixed instance): B=64, S=48, MMAX=24, K=25, V=2048
#define Bdim 64
#define Sdim 48
#define MMAXd 24
#define Kdim (MMAXd + 1)
#define Vdim 2048
#define NSLOT 256

// One wave (64 lanes) per (b,s,k) row of V=2048 logits.
// 4 waves per 256-thread block -> grid = B*S*K/4 = 19200 blocks.
// Structure identical to the harness-verified 704.8us kernel; the one change
// is the label-logit load hoisted BEFORE the bulk row load so its ~500-cycle
// latency hides under the 8 KB of in-flight float4 loads instead of
// serializing after both wave reductions on lane 0.
__global__ __launch_bounds__(256) void ce_main(
    const int* __restrict__ labels,      // (B,S,MMAX)
    const float* __restrict__ logits,    // (B,S,K,V)
    const int* __restrict__ seq_length,  // (B,)
    const int* __restrict__ m_len,       // (B,S)
    const int* __restrict__ end_tok_p,   // scalar
    float* __restrict__ slots)           // NSLOT partial sums
{
    const int wave = threadIdx.x >> 6;
    const int lane = threadIdx.x & 63;
    const int row  = blockIdx.x * 4 + wave;          // [0, B*S*K)

    const int b   = row / (Sdim * Kdim);
    const int rem = row - b * (Sdim * Kdim);
    const int s   = rem / Kdim;
    const int k   = rem - s * Kdim;

    __shared__ float blk[4];

    float nll = 0.0f;
    const int m = m_len[b * Sdim + s];
    if (s < seq_length[b] && k <= m) {               // wave-uniform branch
        const float* rp = logits + (size_t)row * Vdim;

        // Early label-logit load (depends only on labels/end_tok).
        // k == m -> END_TOKEN; else k < m <= MMAX so labels index in-bounds.
        const int lab = (k == m) ? *end_tok_p : labels[(b * Sdim + s) * MMAXd + k];
        const float lab_logit = rp[lab];             // broadcast (same addr all lanes)

        const float4* rp4 = (const float4*)rp;
        float4 d[8];
        #pragma unroll
        for (int j = 0; j < 8; ++j) d[j] = rp4[lane + j * 64];  // coalesced 1KiB/inst

        float mx = -INFINITY;
        #pragma unroll
        for (int j = 0; j < 8; ++j)
            mx = fmaxf(mx, fmaxf(fmaxf(d[j].x, d[j].y), fmaxf(d[j].z, d[j].w)));
        #pragma unroll
        for (int off = 32; off >= 1; off >>= 1)
            mx = fmaxf(mx, __shfl_xor(mx, off, 64));

        float sum = 0.0f;
        #pragma unroll
        for (int j = 0; j < 8; ++j)
            sum += __expf(d[j].x - mx) + __expf(d[j].y - mx)
                 + __expf(d[j].z - mx) + __expf(d[j].w - mx);
        #pragma unroll
        for (int off = 32; off >= 1; off >>= 1)
            sum += __shfl_xor(sum, off, 64);

        nll = __logf(sum) + mx - lab_logit;
    }
    if (lane == 0) blk[wave] = nll;
    __syncthreads();
    if (threadIdx.x == 0) {
        float t = blk[0] + blk[1] + blk[2] + blk[3];
        if (t != 0.0f)
            atomicAdd(&slots[blockIdx.x & (NSLOT - 1)], t);
    }
}

// Single block: sum the NSLOT partials, compute exact valid count, divide.
__global__ __launch_bounds__(256) void ce_final(
    const int* __restrict__ seq_length,
    const int* __restrict__ m_len,
    const float* __restrict__ slots,
    float* __restrict__ out)
{
    const int t = threadIdx.x;
    float s = slots[t];                              // NSLOT == blockDim
    float fc = 0.0f;
    for (int idx = t; idx < Bdim * Sdim; idx += 256) {
        const int b  = idx / Sdim;
        const int ss = idx - b * Sdim;
        if (ss < seq_length[b]) fc += (float)(m_len[idx] + 1);
    }
    #pragma unroll
    for (int off = 32; off >= 1; off >>= 1) {
        s  += __shfl_xor(s,  off, 64);
        fc += __shfl_xor(fc, off, 64);
    }
    __shared__ float ls[4], lc[4];
    const int wave = t >> 6, lane = t & 63;
    if (lane == 0) { ls[wave] = s; lc[wave] = fc; }
    __syncthreads();
    if (t == 0) {
        const float S2 = ls[0] + ls[1] + ls[2] + ls[3];
        const float C2 = lc[0] + lc[1] + lc[2] + lc[3];
        out[0] = S2 / C2;
    }
}

extern "C" void kernel_launch(void* const* d_in, const int* in_sizes, int n_in,
                              void* d_out, int out_size, void* d_ws, size_t ws_size,
                              hipStream_t stream) {
    const int*   labels     = (const int*)d_in[0];
    const float* logits     = (const float*)d_in[1];
    const int*   seq_length = (const int*)d_in[2];
    const int*   m_len      = (const int*)d_in[3];
    // d_in[4] = med_num (=V, structural, unused)
    const int*   end_tok    = (const int*)d_in[5];
    float*       out        = (float*)d_out;
    float*       slots      = (float*)d_ws;

    hipMemsetAsync(slots, 0, NSLOT * sizeof(float), stream);
    ce_main<<<(Bdim * Sdim * Kdim) / 4, 256, 0, stream>>>(
        labels, logits, seq_length, m_len, end_tok, slots);
    ce_final<<<1, 256, 0, stream>>>(seq_length, m_len, slots, out);
}